// Round 9
// baseline (35.419 us; speedup 1.0000x reference)
//
#include <hip/hip_runtime.h>
#include <math.h>

// Problem constants (from reference): B=4, T=4096, H=2048, K=4, FB=H/2=1024
#define HDIM 2048
#define FB   1024
#define NK   4
#define NTOK 16384   // B*T
#define PF   3       // software-pipeline depth (chunks ahead)

// clang ext vector: accepted by __builtin_nontemporal_load (HIP float4 is not)
typedef float f32x4 __attribute__((ext_vector_type(4)));

// ---------------------------------------------------------------------------
// Kernel 1: effective weights  e[k][n] = sum_f w[k][f] * cos(2*pi*f*n/HDIM)
// Folds rfft-real + spectral projection into one (K,H) matrix.
// Integer phase p = (f*n) mod 2048 -> revolutions p/2048 in [0,1):
// v_cos_f32 (__builtin_amdgcn_cosf) takes REVOLUTIONS, so no range
// reduction needed (verified r2-r8: absmax 1.2e-4).
// ---------------------------------------------------------------------------
__global__ __launch_bounds__(256) void build_eff(const float* __restrict__ w,
                                                 float* __restrict__ e) {
    int gid = blockIdx.x * 256 + threadIdx.x;
    int oid = gid >> 4;        // output id 0..8191
    int sub = gid & 15;        // sub-lane within 16-group
    int k = oid >> 11;         // 0..3
    int n = oid & 2047;        // 0..2047
    const float* wk = w + k * FB;

    const float inv = 1.0f / 2048.0f;   // phase -> revolutions
    int step = (n << 4) & 2047;         // phase increment per j (f += 16)
    int p = (n * sub) & 2047;           // phase for f = sub
    float acc = 0.0f;
#pragma unroll 8
    for (int j = 0; j < 64; ++j) {
        acc = fmaf(wk[(j << 4) + sub], __builtin_amdgcn_cosf((float)p * inv), acc);
        p = (p + step) & 2047;
    }
    acc += __shfl_xor(acc, 1);
    acc += __shfl_xor(acc, 2);
    acc += __shfl_xor(acc, 4);
    acc += __shfl_xor(acc, 8);
    if (sub == 0) e[oid] = acc;
}

// ---------------------------------------------------------------------------
// epilogue helper: gate / blend / tanh for one token (compile-time indices
// only after full unroll -> stays in registers)
// ---------------------------------------------------------------------------
__device__ __forceinline__ float finish_tok(float en, const float* a,
                                            const float* th, const float* bl) {
    float energy = sqrtf(en);
    float z = 0.0f;
#pragma unroll
    for (int k = 0; k < NK; ++k)
        if (energy > th[k]) z = fmaf(bl[k], a[k], z);
    return tanhf(z);
}

// ---------------------------------------------------------------------------
// Kernel 2: streaming pass over x — NO LDS this round. e (32 KB) is read via
// plain cached global loads: it exactly fits the 32 KB per-CU L1 and is the
// hottest data on the CU (touched every chunk by every wave), so L1 LRU
// keeps it while nt x-loads stream past without allocating. Removes the
// staging phase + __syncthreads + the 32 MB e-restage L2 burst, and frees
// the LDS occupancy limit: 2048 blocks x 256 thr (2 tokens/wave),
// launch_bounds(256,5) -> 20 waves/CU (vs 16 with the LDS tile).
// 3-deep x pipeline kept from r8 (verified).
// ---------------------------------------------------------------------------
__global__ __launch_bounds__(256, 5) void spectral_main(
    const float* __restrict__ x,
    const float* __restrict__ e,
    const float* __restrict__ thr,
    const float* __restrict__ blend,
    float* __restrict__ out) {
    int tid = threadIdx.x;
    int wave = tid >> 6;
    int lane = tid & 63;
    int tok0 = blockIdx.x * 8 + wave * 2;
    const f32x4* xr = (const f32x4*)x + (size_t)tok0 * (HDIM / 4);
    const f32x4* eg = (const f32x4*)e;

    // register window over chunks; full unroll -> static indices -> registers
    f32x4 xb[8][2];
#pragma unroll
    for (int c = 0; c < PF; ++c)
#pragma unroll
        for (int t = 0; t < 2; ++t)
            xb[c][t] = __builtin_nontemporal_load(&xr[t * 512 + c * 64 + lane]);

    float th[NK], bl[NK];
#pragma unroll
    for (int k = 0; k < NK; ++k) { th[k] = fabsf(thr[k]); bl[k] = blend[k]; }

    float en[2] = {0.f, 0.f};
    float ac[2][NK] = {};

#pragma unroll
    for (int c = 0; c < 8; ++c) {
        // issue chunk c+PF x-loads before consuming chunk c
        if (c + PF < 8) {
#pragma unroll
            for (int t = 0; t < 2; ++t)
                xb[c + PF][t] =
                    __builtin_nontemporal_load(&xr[t * 512 + (c + PF) * 64 + lane]);
        }
        int idx = c * 64 + lane;
        f32x4 ev[NK];
#pragma unroll
        for (int k = 0; k < NK; ++k) ev[k] = eg[k * 512 + idx];   // L1-resident
#pragma unroll
        for (int t = 0; t < 2; ++t) {
            f32x4 v = xb[c][t];
            en[t] = fmaf(v.x, v.x, fmaf(v.y, v.y, fmaf(v.z, v.z, fmaf(v.w, v.w, en[t]))));
#pragma unroll
            for (int k = 0; k < NK; ++k) {
                f32x4 w4 = ev[k];
                ac[t][k] = fmaf(v.x, w4.x, fmaf(v.y, w4.y,
                           fmaf(v.z, w4.z, fmaf(v.w, w4.w, ac[t][k]))));
            }
        }
    }

    // 64-lane butterfly reduction of the 10 accumulators
#pragma unroll
    for (int s = 1; s < 64; s <<= 1) {
#pragma unroll
        for (int t = 0; t < 2; ++t) {
            en[t] += __shfl_xor(en[t], s);
#pragma unroll
            for (int k = 0; k < NK; ++k) ac[t][k] += __shfl_xor(ac[t][k], s);
        }
    }

    if (lane == 0) {
        float2 o;
        o.x = finish_tok(en[0], ac[0], th, bl);
        o.y = finish_tok(en[1], ac[1], th, bl);
        *(float2*)(out + tok0) = o;   // tok0 even -> 8B aligned
    }
}

extern "C" void kernel_launch(void* const* d_in, const int* in_sizes, int n_in,
                              void* d_out, int out_size, void* d_ws, size_t ws_size,
                              hipStream_t stream) {
    const float* x     = (const float*)d_in[0];  // (B,T,H) f32
    const float* w     = (const float*)d_in[1];  // (K,FB)  f32
    const float* thr   = (const float*)d_in[2];  // (K,)    f32
    const float* blend = (const float*)d_in[3];  // (1,K)   f32
    float* out = (float*)d_out;                  // (B,T,1) f32
    float* e   = (float*)d_ws;                   // K*HDIM f32 = 32 KB scratch

    build_eff<<<512, 256, 0, stream>>>(w, e);
    spectral_main<<<NTOK / 8, 256, 0, stream>>>(x, e, thr, blend, out);
}

// Round 10
// 32.159 us; speedup vs baseline: 1.1014x; 1.1014x over previous
//
#include <hip/hip_runtime.h>
#include <math.h>

// Problem constants (from reference): B=4, T=4096, H=2048, K=4, FB=H/2=1024
#define HDIM 2048
#define FB   1024
#define NK   4
#define NTOK 16384   // B*T
#define PF   4       // software-pipeline depth (chunks ahead)

// clang ext vector: accepted by __builtin_nontemporal_load (HIP float4 is not)
typedef float f32x4 __attribute__((ext_vector_type(4)));

// ---------------------------------------------------------------------------
// Kernel 1: effective weights  e[k][n] = sum_f w[k][f] * cos(2*pi*f*n/HDIM)
// Folds rfft-real + spectral projection into one (K,H) matrix.
// Integer phase p = (f*n) mod 2048 -> revolutions p/2048 in [0,1):
// v_cos_f32 (__builtin_amdgcn_cosf) takes REVOLUTIONS, so no range
// reduction needed (verified r2-r8: absmax 1.2e-4).
// ---------------------------------------------------------------------------
__global__ __launch_bounds__(256) void build_eff(const float* __restrict__ w,
                                                 float* __restrict__ e) {
    int gid = blockIdx.x * 256 + threadIdx.x;
    int oid = gid >> 4;        // output id 0..8191
    int sub = gid & 15;        // sub-lane within 16-group
    int k = oid >> 11;         // 0..3
    int n = oid & 2047;        // 0..2047
    const float* wk = w + k * FB;

    const float inv = 1.0f / 2048.0f;   // phase -> revolutions
    int step = (n << 4) & 2047;         // phase increment per j (f += 16)
    int p = (n * sub) & 2047;           // phase for f = sub
    float acc = 0.0f;
#pragma unroll 8
    for (int j = 0; j < 64; ++j) {
        acc = fmaf(wk[(j << 4) + sub], __builtin_amdgcn_cosf((float)p * inv), acc);
        p = (p + step) & 2047;
    }
    acc += __shfl_xor(acc, 1);
    acc += __shfl_xor(acc, 2);
    acc += __shfl_xor(acc, 4);
    acc += __shfl_xor(acc, 8);
    if (sub == 0) e[oid] = acc;
}

// ---------------------------------------------------------------------------
// epilogue helper: gate / blend / tanh for one token (compile-time indices
// only after full unroll -> stays in registers)
// ---------------------------------------------------------------------------
__device__ __forceinline__ float finish_tok(float en, const float* a,
                                            const float* th, const float* bl) {
    float energy = sqrtf(en);
    float z = 0.0f;
#pragma unroll
    for (int k = 0; k < NK; ++k)
        if (energy > th[k]) z = fmaf(bl[k], a[k], z);
    return tanhf(z);
}

// ---------------------------------------------------------------------------
// Kernel 2: streaming pass over x (r8 structure — best verified 32.7us —
// with PF 3->4). Per wave: 4 consecutive tokens, 8 chunks of 1KB each.
//   - LDS e-tile (32KB): e reads ride the DS pipe; VMEM pipe exclusively
//     for the x stream (r9 showed global-e regresses: 35.4us).
//   - xb[8][4] register window, fully unrolled: chunk c+PF's nt-loads issued
//     BEFORE chunk c's FMAs -> steady-state 16KB/wave in flight, wave never
//     drains vmcnt to 0 mid-loop. Liveness (PF+1)*16 = 80 VGPR, no spill.
//   - chunks 0..PF-1 issued before e-staging + barrier (HBM stream at t=0;
//     the barrier's vmcnt drain is exactly the prefetch window).
//   - nt loads: stream-once x, no cache-alloc churn (r7: nt > plain).
//   - __launch_bounds__(256,4): VGPR<=128, 4 blocks/CU with 32KB LDS.
// Grid: NTOK/16 = 1024 blocks x 256 threads (4 waves x 4 tokens).
// ---------------------------------------------------------------------------
__global__ __launch_bounds__(256, 4) void spectral_main(
    const float* __restrict__ x,
    const float* __restrict__ e,
    const float* __restrict__ thr,
    const float* __restrict__ blend,
    float* __restrict__ out) {
    __shared__ f32x4 els[NK * HDIM / 4];   // 2048 f32x4 = 32 KB

    int tid = threadIdx.x;
    int wave = tid >> 6;
    int lane = tid & 63;
    int tok0 = blockIdx.x * 16 + wave * 4;
    const f32x4* xr = (const f32x4*)x + (size_t)tok0 * (HDIM / 4);

    // register window over chunks; full unroll -> static indices -> registers
    f32x4 xb[8][4];

    // --- issue chunks 0..PF-1 before staging barrier ----------------------
#pragma unroll
    for (int c = 0; c < PF; ++c)
#pragma unroll
        for (int t = 0; t < 4; ++t)
            xb[c][t] = __builtin_nontemporal_load(&xr[t * 512 + c * 64 + lane]);

    // --- stage e into LDS (L2-hot after build_eff) ------------------------
    const f32x4* eg = (const f32x4*)e;
#pragma unroll
    for (int i = 0; i < 8; ++i) els[i * 256 + tid] = eg[i * 256 + tid];

    float th[NK], bl[NK];
#pragma unroll
    for (int k = 0; k < NK; ++k) { th[k] = fabsf(thr[k]); bl[k] = blend[k]; }

    __syncthreads();

    float en[4] = {0.f, 0.f, 0.f, 0.f};
    float ac[4][NK] = {};

#pragma unroll
    for (int c = 0; c < 8; ++c) {
        // issue chunk c+PF loads before consuming chunk c
        if (c + PF < 8) {
#pragma unroll
            for (int t = 0; t < 4; ++t)
                xb[c + PF][t] =
                    __builtin_nontemporal_load(&xr[t * 512 + (c + PF) * 64 + lane]);
        }
        int idx = c * 64 + lane;
        f32x4 ev[NK];
#pragma unroll
        for (int k = 0; k < NK; ++k) ev[k] = els[k * 512 + idx];
#pragma unroll
        for (int t = 0; t < 4; ++t) {
            f32x4 v = xb[c][t];
            en[t] = fmaf(v.x, v.x, fmaf(v.y, v.y, fmaf(v.z, v.z, fmaf(v.w, v.w, en[t]))));
#pragma unroll
            for (int k = 0; k < NK; ++k) {
                f32x4 w4 = ev[k];
                ac[t][k] = fmaf(v.x, w4.x, fmaf(v.y, w4.y,
                           fmaf(v.z, w4.z, fmaf(v.w, w4.w, ac[t][k]))));
            }
        }
    }

    // 64-lane butterfly reduction of the 20 accumulators
#pragma unroll
    for (int s = 1; s < 64; s <<= 1) {
#pragma unroll
        for (int t = 0; t < 4; ++t) {
            en[t] += __shfl_xor(en[t], s);
#pragma unroll
            for (int k = 0; k < NK; ++k) ac[t][k] += __shfl_xor(ac[t][k], s);
        }
    }

    if (lane == 0) {
        f32x4 o;
        o.x = finish_tok(en[0], ac[0], th, bl);
        o.y = finish_tok(en[1], ac[1], th, bl);
        o.z = finish_tok(en[2], ac[2], th, bl);
        o.w = finish_tok(en[3], ac[3], th, bl);
        *(f32x4*)(out + tok0) = o;   // tok0 % 4 == 0 -> 16B aligned
    }
}

extern "C" void kernel_launch(void* const* d_in, const int* in_sizes, int n_in,
                              void* d_out, int out_size, void* d_ws, size_t ws_size,
                              hipStream_t stream) {
    const float* x     = (const float*)d_in[0];  // (B,T,H) f32
    const float* w     = (const float*)d_in[1];  // (K,FB)  f32
    const float* thr   = (const float*)d_in[2];  // (K,)    f32
    const float* blend = (const float*)d_in[3];  // (1,K)   f32
    float* out = (float*)d_out;                  // (B,T,1) f32
    float* e   = (float*)d_ws;                   // K*HDIM f32 = 32 KB scratch

    build_eff<<<512, 256, 0, stream>>>(w, e);
    spectral_main<<<NTOK / 16, 256, 0, stream>>>(x, e, thr, blend, out);
}